// Round 1
// baseline (441.609 us; speedup 1.0000x reference)
//
#include <hip/hip_runtime.h>
#include <stdint.h>

#define Bq 8
#define Mq 1024
#define Hq 512
#define NHq 8
#define Dq 64
#define SPANq 1024
#define MKq 2048
#define CHUNK 512
#define SW 520   // S row stride (floats)
#define PW 552   // Psk row stride (ushorts), 544 used

typedef __bf16 bf16x8 __attribute__((ext_vector_type(8)));
typedef float f32x4 __attribute__((ext_vector_type(4)));
typedef unsigned short ushort8 __attribute__((ext_vector_type(8)));

static __device__ __forceinline__ unsigned short f2bf(float f) {
  union { float f; unsigned u; } x; x.f = f;
  unsigned r = x.u + 0x7FFFu + ((x.u >> 16) & 1u);
  return (unsigned short)(r >> 16);
}

static __device__ __forceinline__ f32x4 mfma_bf16(bf16x8 a, bf16x8 b, f32x4 c) {
  return __builtin_amdgcn_mfma_f32_16x16x32_bf16(a, b, c, 0, 0, 0);
}

// ---------------- prep: transpose+convert weights (WT[o][i]=W[i][o]) and pos (posT[s][d]=pos[d][s])
__global__ __launch_bounds__(256) void prep_transpose(
    const float* __restrict__ Wq, const float* __restrict__ Wk,
    const float* __restrict__ Wv, const float* __restrict__ Wo,
    const float* __restrict__ pos,
    unsigned short* __restrict__ WTq, unsigned short* __restrict__ WTk,
    unsigned short* __restrict__ WTv, unsigned short* __restrict__ WTo,
    unsigned short* __restrict__ posT) {
  __shared__ float tile[64][65];
  const int bid = blockIdx.x;
  const float* src; unsigned short* dst;
  int src_stride, dst_stride, i0, o0;
  if (bid < 256) {
    const int w = bid >> 6, t = bid & 63;
    src = (w == 0) ? Wq : (w == 1) ? Wk : (w == 2) ? Wv : Wo;
    dst = (w == 0) ? WTq : (w == 1) ? WTk : (w == 2) ? WTv : WTo;
    src_stride = Hq; dst_stride = Hq;
    i0 = (t >> 3) * 64; o0 = (t & 7) * 64;
  } else {
    const int t = bid - 256;
    src = pos; dst = posT;
    src_stride = SPANq; dst_stride = Dq;
    i0 = 0; o0 = t * 64;
  }
  const int tid = threadIdx.x;
  for (int e = tid; e < 4096; e += 256) {
    const int r = e >> 6, c = e & 63;
    tile[r][c] = src[(size_t)(i0 + r) * src_stride + o0 + c];
  }
  __syncthreads();
  for (int e = tid; e < 4096; e += 256) {
    const int r = e >> 6, c = e & 63;
    dst[(size_t)(o0 + r) * dst_stride + i0 + c] = f2bf(tile[c][r]);
  }
}

// ---------------- projection / output GEMM
// C[r][c] = sum_k X[r][k] * W[k][c], staged via WT[c][k].
// mode 0: q -> qb[(b*8+head)*M + t][d]      (fp32 X)
// mode 1: k -> kb[(b*8+head)*MK + t][d]     (fp32 X)
// mode 2: v -> vT[(b*8+head)*64 + d][t]     (fp32 X)
// mode 3: out = ctx(bf16) @ Wo -> fp32 row-major
__global__ __launch_bounds__(256) void gemm_proj(
    const float* __restrict__ X, const unsigned short* __restrict__ Xb,
    const unsigned short* __restrict__ WT,
    unsigned short* __restrict__ outb, float* __restrict__ outf,
    int mode, int tshift) {
  __shared__ unsigned short As[64][40];
  __shared__ unsigned short Bs[64][40];
  const int tid = threadIdx.x;
  const int wave = tid >> 6, lane = tid & 63;
  const int quad = lane >> 4, l16 = lane & 15;
  const size_t m0 = (size_t)blockIdx.x * 64;
  const int n0 = blockIdx.y * 64;
  const int r_st = tid >> 2;
  const int c_st = (tid & 3) * 8;

  f32x4 acc[4] = {{0.f,0.f,0.f,0.f},{0.f,0.f,0.f,0.f},{0.f,0.f,0.f,0.f},{0.f,0.f,0.f,0.f}};

  for (int k0 = 0; k0 < Hq; k0 += 32) {
    if (mode == 3) {
      const ushort8 va = *(const ushort8*)(Xb + (m0 + r_st) * Hq + k0 + c_st);
      *(ushort8*)(&As[r_st][c_st]) = va;
    } else {
      const float* src = X + (m0 + r_st) * Hq + k0 + c_st;
      const f32x4 f0 = *(const f32x4*)src;
      const f32x4 f1 = *(const f32x4*)(src + 4);
      ushort8 h;
      h[0] = f2bf(f0[0]); h[1] = f2bf(f0[1]); h[2] = f2bf(f0[2]); h[3] = f2bf(f0[3]);
      h[4] = f2bf(f1[0]); h[5] = f2bf(f1[1]); h[6] = f2bf(f1[2]); h[7] = f2bf(f1[3]);
      *(ushort8*)(&As[r_st][c_st]) = h;
    }
    {
      const ushort8 vb = *(const ushort8*)(WT + (size_t)(n0 + r_st) * Hq + k0 + c_st);
      *(ushort8*)(&Bs[r_st][c_st]) = vb;
    }
    __syncthreads();
    const bf16x8 bfrag = *(const bf16x8*)(&Bs[wave * 16 + l16][quad * 8]);
#pragma unroll
    for (int mt = 0; mt < 4; mt++) {
      const bf16x8 afrag = *(const bf16x8*)(&As[mt * 16 + l16][quad * 8]);
      acc[mt] = mfma_bf16(afrag, bfrag, acc[mt]);
    }
    __syncthreads();
  }

  const int c_loc = n0 + wave * 16 + l16;
  const int head = c_loc >> 6;
  const int d = c_loc & 63;
#pragma unroll
  for (int mt = 0; mt < 4; mt++) {
#pragma unroll
    for (int r = 0; r < 4; r++) {
      const size_t r_glob = m0 + mt * 16 + quad * 4 + r;
      const float val = acc[mt][r];
      if (mode == 3) {
        outf[r_glob * Hq + c_loc] = val;
      } else {
        const size_t t = r_glob & (((size_t)1 << tshift) - 1);
        const size_t b = r_glob >> tshift;
        const size_t n = b * NHq + head;
        if (mode == 2) {
          outb[(n * Dq + d) * MKq + t] = f2bf(val);
        } else {
          const size_t Tlen = (size_t)1 << tshift;
          outb[(n * Tlen + t) * Dq + d] = f2bf(val);
        }
      }
    }
  }
}

// ---------------- banded attention with relative positions
// block = (16 queries) x (one head n = b*8+head); logits[m][s] = q_m . k_{m+s} + q_m . pos[:,s]
__global__ __launch_bounds__(256) void attn_kernel(
    const unsigned short* __restrict__ qb, const unsigned short* __restrict__ kb,
    const unsigned short* __restrict__ vTb, const unsigned short* __restrict__ posT,
    unsigned short* __restrict__ ctx) {
  __shared__ float S[16][SW];
  __shared__ unsigned short Psk[16][PW];
  __shared__ float Mrow[16], Zacc[16], Alpha[16];

  const int tid = threadIdx.x;
  const int wave = tid >> 6, lane = tid & 63;
  const int quad = lane >> 4, l16 = lane & 15;
  const int qt = blockIdx.x, n = blockIdx.y;
  const int m0 = qt * 16;

  // Q fragments: A[m=l16][k=quad*8+j], K-dim = d (64 -> two frags)
  const unsigned short* qbase = qb + ((size_t)n * Mq + m0 + l16) * Dq;
  const bf16x8 qf0 = *(const bf16x8*)(qbase + quad * 8);
  const bf16x8 qf1 = *(const bf16x8*)(qbase + 32 + quad * 8);

  {
    unsigned* p = (unsigned*)&Psk[0][0];
    for (int i = tid; i < 16 * PW / 2; i += 256) p[i] = 0u;
    if (tid < 16) { Mrow[tid] = -3.0e38f; Zacc[tid] = 0.f; }
  }

  f32x4 o = {0.f, 0.f, 0.f, 0.f};

  for (int c = 0; c < 2; c++) {
    const int sbase = c * CHUNK;
    // --- pos logits: S[m][sl] = q_m . pos[:, sbase+sl]
    for (int st = wave; st < CHUNK / 16; st += 4) {
      const unsigned short* pb = posT + (size_t)(sbase + st * 16 + l16) * Dq;
      const bf16x8 b0 = *(const bf16x8*)(pb + quad * 8);
      const bf16x8 b1 = *(const bf16x8*)(pb + 32 + quad * 8);
      f32x4 a = {0.f, 0.f, 0.f, 0.f};
      a = mfma_bf16(qf0, b0, a);
      a = mfma_bf16(qf1, b1, a);
#pragma unroll
      for (int r = 0; r < 4; r++) S[quad * 4 + r][st * 16 + l16] = a[r];
    }
    __syncthreads();
    // --- ctx logits: (m,j) tiles, scatter-add at sl = j - m - sbase (unique writer per元素)
    for (int jt = wave; jt < 33; jt += 4) {
      const int j0 = m0 + sbase + jt * 16;
      const unsigned short* kbp = kb + ((size_t)n * MKq + j0 + l16) * Dq;
      const bf16x8 b0 = *(const bf16x8*)(kbp + quad * 8);
      const bf16x8 b1 = *(const bf16x8*)(kbp + 32 + quad * 8);
      f32x4 a = {0.f, 0.f, 0.f, 0.f};
      a = mfma_bf16(qf0, b0, a);
      a = mfma_bf16(qf1, b1, a);
#pragma unroll
      for (int r = 0; r < 4; r++) {
        const int mi = quad * 4 + r;
        const int sl = jt * 16 + l16 - mi;
        if (sl >= 0 && sl < CHUNK) S[mi][sl] += a[r];
      }
    }
    __syncthreads();
    // --- online softmax over this chunk; probs stored pre-skewed: Psk[m][sl+m]
    {
      const int r = tid >> 4, li = tid & 15;
      float mx = -3.0e38f;
      for (int s = li; s < CHUNK; s += 16) mx = fmaxf(mx, S[r][s]);
#pragma unroll
      for (int off = 8; off; off >>= 1) mx = fmaxf(mx, __shfl_xor(mx, off, 64));
      const float m_old = Mrow[r];
      const float m_new = fmaxf(m_old, mx);
      float sum = 0.f;
      for (int s = li; s < CHUNK; s += 16) {
        const float e = __expf((S[r][s] - m_new) * 0.125f);
        sum += e;
        Psk[r][s + r] = f2bf(e);
      }
#pragma unroll
      for (int off = 8; off; off >>= 1) sum += __shfl_xor(sum, off, 64);
      if (li == 0) {
        const float al = __expf((m_old - m_new) * 0.125f);
        Zacc[r] = Zacc[r] * al + sum;
        Mrow[r] = m_new;
        Alpha[r] = al;
      }
    }
    __syncthreads();
    // --- PV: out[m][d] += sum_jl Psk[m][jl] * v[m0+sbase+jl][d]
    {
#pragma unroll
      for (int r = 0; r < 4; r++) o[r] *= Alpha[quad * 4 + r];
      const unsigned short* vbase = vTb + ((size_t)n * Dq + wave * 16 + l16) * MKq;
      const int jb = m0 + sbase;
      for (int ks = 0; ks < 17; ks++) {
        const int jl = ks * 32 + quad * 8;
        const bf16x8 af = *(const bf16x8*)(&Psk[l16][jl]);
        int j = jb + jl;
        if (j > MKq - 8) j = MKq - 8;  // p==0 beyond band; clamp keeps load in-bounds
        const bf16x8 bf = *(const bf16x8*)(vbase + j);
        o = mfma_bf16(af, bf, o);
      }
    }
  }

  // epilogue: ctx[b*M + m][head*64 + d] = o / Z
  const int cc = (n & 7) * Dq + wave * 16 + l16;
  const size_t rowb = (size_t)(n >> 3) * Mq + m0;
#pragma unroll
  for (int r = 0; r < 4; r++) {
    const int mi = quad * 4 + r;
    ctx[(rowb + mi) * Hq + cc] = f2bf(o[r] / Zacc[mi]);
  }
}

extern "C" void kernel_launch(void* const* d_in, const int* in_sizes, int n_in,
                              void* d_out, int out_size, void* d_ws, size_t ws_size,
                              hipStream_t stream) {
  const float* query = (const float*)d_in[0];
  const float* key   = (const float*)d_in[1];
  const float* value = (const float*)d_in[2];
  const float* pos   = (const float*)d_in[3];
  const float* Wq    = (const float*)d_in[4];
  const float* Wk    = (const float*)d_in[5];
  const float* Wv    = (const float*)d_in[6];
  const float* Wo    = (const float*)d_in[7];
  float* out = (float*)d_out;

  char* w = (char*)d_ws;
  unsigned short* qbuf = (unsigned short*)w; w += (size_t)64 * Mq * Dq * 2;    // 8 MB
  unsigned short* kbuf = (unsigned short*)w; w += (size_t)64 * MKq * Dq * 2;   // 16 MB
  unsigned short* vT   = (unsigned short*)w; w += (size_t)64 * Dq * MKq * 2;   // 16 MB
  unsigned short* posT = (unsigned short*)w; w += (size_t)SPANq * Dq * 2;      // 128 KB
  unsigned short* WTq  = (unsigned short*)w; w += (size_t)Hq * Hq * 2;
  unsigned short* WTk  = (unsigned short*)w; w += (size_t)Hq * Hq * 2;
  unsigned short* WTv  = (unsigned short*)w; w += (size_t)Hq * Hq * 2;
  unsigned short* WTo  = (unsigned short*)w; w += (size_t)Hq * Hq * 2;
  unsigned short* ctx  = (unsigned short*)w; w += (size_t)Bq * Mq * Hq * 2;    // 8 MB

  prep_transpose<<<272, 256, 0, stream>>>(Wq, Wk, Wv, Wo, pos, WTq, WTk, WTv, WTo, posT);
  gemm_proj<<<dim3(128, 8), 256, 0, stream>>>(query, nullptr, WTq, qbuf, nullptr, 0, 10);
  gemm_proj<<<dim3(256, 8), 256, 0, stream>>>(key,   nullptr, WTk, kbuf, nullptr, 1, 11);
  gemm_proj<<<dim3(256, 8), 256, 0, stream>>>(value, nullptr, WTv, vT,   nullptr, 2, 11);
  attn_kernel<<<dim3(64, 64), 256, 0, stream>>>(qbuf, kbuf, vT, posT, ctx);
  gemm_proj<<<dim3(128, 8), 256, 0, stream>>>(nullptr, ctx, WTo, nullptr, out, 3, 10);
}

// Round 3
// 397.581 us; speedup vs baseline: 1.1107x; 1.1107x over previous
//
#include <hip/hip_runtime.h>
#include <stdint.h>

#define Bq 8
#define Mq 1024
#define Hq 512
#define NHq 8
#define Dq 64
#define SPANq 1024
#define MKq 2048
#define PR 292   // attn LDS row stride (ushorts/f16)

typedef __bf16 bf16x8 __attribute__((ext_vector_type(8)));
typedef _Float16 f16x8 __attribute__((ext_vector_type(8)));
typedef float f32x4 __attribute__((ext_vector_type(4)));
typedef unsigned short ushort8 __attribute__((ext_vector_type(8)));
typedef unsigned int uint2v __attribute__((ext_vector_type(2)));

static __device__ __forceinline__ unsigned short f2bf(float f) {
  union { float f; unsigned u; } x; x.f = f;
  unsigned r = x.u + 0x7FFFu + ((x.u >> 16) & 1u);
  return (unsigned short)(r >> 16);
}

static __device__ __forceinline__ unsigned pk_f16(float a, float b) {
  return __builtin_bit_cast(unsigned, __builtin_amdgcn_cvt_pkrtz(a, b));
}

static __device__ __forceinline__ f32x4 mfma_bf16(bf16x8 a, bf16x8 b, f32x4 c) {
  return __builtin_amdgcn_mfma_f32_16x16x32_bf16(a, b, c, 0, 0, 0);
}
static __device__ __forceinline__ f32x4 mfma_f16(f16x8 a, f16x8 b, f32x4 c) {
  return __builtin_amdgcn_mfma_f32_16x16x32_f16(a, b, c, 0, 0, 0);
}

// ---------------- prep: transpose+convert weights (WT[o][i]=W[i][o]) and pos (posT[s][d]=pos[d][s])
__global__ __launch_bounds__(256) void prep_transpose(
    const float* __restrict__ Wq, const float* __restrict__ Wk,
    const float* __restrict__ Wv, const float* __restrict__ Wo,
    const float* __restrict__ pos,
    unsigned short* __restrict__ WTq, unsigned short* __restrict__ WTk,
    unsigned short* __restrict__ WTv, unsigned short* __restrict__ WTo,
    unsigned short* __restrict__ posT) {
  __shared__ float tile[64][65];
  const int bid = blockIdx.x;
  const float* src; unsigned short* dst;
  int src_stride, dst_stride, i0, o0;
  if (bid < 256) {
    const int w = bid >> 6, t = bid & 63;
    src = (w == 0) ? Wq : (w == 1) ? Wk : (w == 2) ? Wv : Wo;
    dst = (w == 0) ? WTq : (w == 1) ? WTk : (w == 2) ? WTv : WTo;
    src_stride = Hq; dst_stride = Hq;
    i0 = (t >> 3) * 64; o0 = (t & 7) * 64;
  } else {
    const int t = bid - 256;
    src = pos; dst = posT;
    src_stride = SPANq; dst_stride = Dq;
    i0 = 0; o0 = t * 64;
  }
  const int tid = threadIdx.x;
  for (int e = tid; e < 4096; e += 256) {
    const int r = e >> 6, c = e & 63;
    tile[r][c] = src[(size_t)(i0 + r) * src_stride + o0 + c];
  }
  __syncthreads();
  for (int e = tid; e < 4096; e += 256) {
    const int r = e >> 6, c = e & 63;
    dst[(size_t)(o0 + r) * dst_stride + i0 + c] = f2bf(tile[c][r]);
  }
}

// ---------------- 128x128 GEMM, C[r][c] = sum_k X[r][k] * WT[c][k]
// mode 0: q -> qb[(b*8+head)*M + t][d]   bf16   (fp32 X)
// mode 1: k -> kb[(b*8+head)*MK + t][d]  bf16   (fp32 X)
// mode 2: v -> vT[(b*8+head)*64 + d][t]  f16    (fp32 X, LDS-transposed epilogue)
// mode 3: out = ctx(bf16) @ Wo -> fp32 row-major
__global__ __launch_bounds__(256) void gemm128(
    const float* __restrict__ X, const unsigned short* __restrict__ Xb,
    const unsigned short* __restrict__ WT,
    unsigned short* __restrict__ outb, _Float16* __restrict__ outv,
    float* __restrict__ outf, int mode, int tshift) {
  __shared__ unsigned short sh[18432];
  unsigned short* As = sh;            // [128][40]
  unsigned short* Bs = sh + 5120;     // [128][40]
  const int tid = threadIdx.x;
  const int wave = tid >> 6, lane = tid & 63;
  const int q = lane >> 4, l16 = lane & 15;
  const int wy = wave >> 1, wx = wave & 1;
  const size_t m0 = (size_t)blockIdx.x * 128;
  const int n0 = blockIdx.y * 128;
  const int row = tid >> 1, kc0 = (tid & 1) * 16;

  f32x4 acc[4][4] = {};

  for (int k0 = 0; k0 < Hq; k0 += 32) {
    if (mode == 3) {
      const unsigned short* xp = Xb + (m0 + row) * Hq + k0 + kc0;
      *(ushort8*)(As + row * 40 + kc0) = *(const ushort8*)xp;
      *(ushort8*)(As + row * 40 + kc0 + 8) = *(const ushort8*)(xp + 8);
    } else {
      const float* xp = X + (m0 + row) * Hq + k0 + kc0;
      const f32x4 f0 = *(const f32x4*)xp;
      const f32x4 f1 = *(const f32x4*)(xp + 4);
      const f32x4 f2 = *(const f32x4*)(xp + 8);
      const f32x4 f3 = *(const f32x4*)(xp + 12);
      ushort8 h0, h1;
      h0[0] = f2bf(f0[0]); h0[1] = f2bf(f0[1]); h0[2] = f2bf(f0[2]); h0[3] = f2bf(f0[3]);
      h0[4] = f2bf(f1[0]); h0[5] = f2bf(f1[1]); h0[6] = f2bf(f1[2]); h0[7] = f2bf(f1[3]);
      h1[0] = f2bf(f2[0]); h1[1] = f2bf(f2[1]); h1[2] = f2bf(f2[2]); h1[3] = f2bf(f2[3]);
      h1[4] = f2bf(f3[0]); h1[5] = f2bf(f3[1]); h1[6] = f2bf(f3[2]); h1[7] = f2bf(f3[3]);
      *(ushort8*)(As + row * 40 + kc0) = h0;
      *(ushort8*)(As + row * 40 + kc0 + 8) = h1;
    }
    {
      const unsigned short* wp = WT + (size_t)(n0 + row) * Hq + k0 + kc0;
      *(ushort8*)(Bs + row * 40 + kc0) = *(const ushort8*)wp;
      *(ushort8*)(Bs + row * 40 + kc0 + 8) = *(const ushort8*)(wp + 8);
    }
    __syncthreads();
    bf16x8 af[4], bf[4];
#pragma unroll
    for (int mt = 0; mt < 4; mt++)
      af[mt] = *(const bf16x8*)(As + (wy * 64 + mt * 16 + l16) * 40 + q * 8);
#pragma unroll
    for (int nt = 0; nt < 4; nt++)
      bf[nt] = *(const bf16x8*)(Bs + (wx * 64 + nt * 16 + l16) * 40 + q * 8);
#pragma unroll
    for (int mt = 0; mt < 4; mt++)
#pragma unroll
      for (int nt = 0; nt < 4; nt++)
        acc[mt][nt] = mfma_bf16(af[mt], bf[nt], acc[mt][nt]);
    __syncthreads();
  }

  if (mode == 2) {
    // transpose epilogue: per-wave 64x64 tile -> vT[(b*8+head)*64 + d][t] f16
    _Float16* tr = (_Float16*)sh + wave * 4608;  // [64][72]
#pragma unroll
    for (int nt = 0; nt < 4; nt++)
#pragma unroll
      for (int mt = 0; mt < 4; mt++)
#pragma unroll
        for (int r = 0; r < 4; r++)
          tr[(nt * 16 + l16) * 72 + mt * 16 + q * 4 + r] = (_Float16)acc[mt][nt][r];
    const int head = blockIdx.y * 2 + wx;
    const int mrow0 = (int)m0 + wy * 64;
    const int Tlen = 1 << tshift;
    const int b = mrow0 >> tshift, t0 = mrow0 & (Tlen - 1);
#pragma unroll
    for (int it = 0; it < 8; it++) {
      const int dl = it * 8 + (lane >> 3), tl = (lane & 7) * 8;
      const f16x8 v = *(const f16x8*)(tr + dl * 72 + tl);
      *(f16x8*)(outv + ((size_t)((b * 8 + head) * 64 + dl)) * Tlen + t0 + tl) = v;
    }
    return;
  }

  const int Tlen = 1 << tshift;
#pragma unroll
  for (int mt = 0; mt < 4; mt++) {
#pragma unroll
    for (int nt = 0; nt < 4; nt++) {
      const int c = n0 + wx * 64 + nt * 16 + l16;
#pragma unroll
      for (int r = 0; r < 4; r++) {
        const int m = (int)m0 + wy * 64 + mt * 16 + q * 4 + r;
        const float val = acc[mt][nt][r];
        if (mode == 3) {
          outf[(size_t)m * Hq + c] = val;
        } else {
          const int b = m >> tshift, t = m & (Tlen - 1);
          const int head = c >> 6, d = c & 63;
          outb[(((size_t)(b * 8 + head) << tshift) + t) * 64 + d] = f2bf(val);
        }
      }
    }
  }
}

// ---------------- banded attention, register-resident softmax, no barriers
// block = 64 queries x one head; wave owns 16 queries. S^T = K.Q^T so each
// lane owns query row m = lane&15; pos logits skewed through wave-private LDS.
__global__ void attn2(const unsigned short* __restrict__ qb,
                      const unsigned short* __restrict__ kb,
                      const _Float16* __restrict__ vT,
                      const unsigned short* __restrict__ posT,
                      unsigned short* __restrict__ ctx) {
  __shared__ unsigned short Psh[4 * 16 * PR];  // 37376 B, wave-private rows

  const int tid = threadIdx.x;
  const int wave = tid >> 6, lane = tid & 63;
  const int q = lane >> 4, l16 = lane & 15;
  const int n = blockIdx.y;
  const int m0w = blockIdx.x * 64 + wave * 16;

  unsigned short* row = Psh + (wave * 16 + l16) * PR;

  // Q fragments (B-operand role): col m = l16, k = q*8+j over d
  const unsigned short* qbase = qb + ((size_t)n * Mq + m0w + l16) * Dq;
  const bf16x8 qf0 = *(const bf16x8*)(qbase + q * 8);
  const bf16x8 qf1 = *(const bf16x8*)(qbase + 32 + q * 8);

  const unsigned short* kbn = kb + (size_t)n * MKq * Dq;
  const _Float16* vbn = vT + (size_t)n * Dq * MKq;

  f32x4 O[4] = {};
  float zrow = 0.f, mrow = -1e30f;

  for (int c = 0; c < 4; c++) {
    const int sbase = c << 8;
    const int j00 = m0w + sbase;

    // --- stage A: pos logits -> LDS skewed: PosSk[m][16 + s + m]
#pragma unroll
    for (int t = 0; t < 16; t++) {
      const unsigned short* pp = posT + (size_t)(sbase + t * 16 + l16) * Dq;
      f32x4 a = {};
      a = mfma_bf16(*(const bf16x8*)(pp + q * 8), qf0, a);
      a = mfma_bf16(*(const bf16x8*)(pp + 32 + q * 8), qf1, a);
      const int cw = 16 + t * 16 + 4 * q + l16;
      row[cw + 0] = f2bf(a[0]);
      row[cw + 1] = f2bf(a[1]);
      row[cw + 2] = f2bf(a[2]);
      row[cw + 3] = f2bf(a[3]);
    }

    // --- stage B: ctx logits S^T[j][m] + skewed pos readback + band mask
    f32x4 S[17];
#pragma unroll
    for (int t = 0; t < 17; t++) {
      const unsigned short* kp = kbn + (size_t)(j00 + t * 16 + l16) * Dq;
      f32x4 a = {};
      a = mfma_bf16(*(const bf16x8*)(kp + q * 8), qf0, a);
      a = mfma_bf16(*(const bf16x8*)(kp + 32 + q * 8), qf1, a);
      const uint2v pv = *(const uint2v*)(row + 16 + t * 16 + 4 * q);
      a[0] += __uint_as_float(pv.x << 16);
      a[1] += __uint_as_float(pv.x & 0xffff0000u);
      a[2] += __uint_as_float(pv.y << 16);
      a[3] += __uint_as_float(pv.y & 0xffff0000u);
      if (t == 0) {
#pragma unroll
        for (int r = 0; r < 4; r++) a[r] = (4 * q + r >= l16) ? a[r] : -1e30f;
      }
      if (t == 16) {
#pragma unroll
        for (int r = 0; r < 4; r++) a[r] = (4 * q + r < l16) ? a[r] : -1e30f;
      }
      S[t] = a;
    }

    // --- online softmax, fully in registers (row m = l16 per lane)
    float mx = -1e30f;
#pragma unroll
    for (int t = 0; t < 17; t++)
      mx = fmaxf(mx, fmaxf(fmaxf(S[t][0], S[t][1]), fmaxf(S[t][2], S[t][3])));
    mx = fmaxf(mx, __shfl_xor(mx, 16, 64));
    mx = fmaxf(mx, __shfl_xor(mx, 32, 64));
    const float m_new = fmaxf(mrow, mx);
    const float alpha = __expf((mrow - m_new) * 0.125f);
    float zs = 0.f;
#pragma unroll
    for (int t = 0; t < 17; t++) {
#pragma unroll
      for (int r = 0; r < 4; r++) {
        const float e = __expf((S[t][r] - m_new) * 0.125f);
        S[t][r] = e; zs += e;
      }
    }
    zs += __shfl_xor(zs, 16, 64);
    zs += __shfl_xor(zs, 32, 64);
    zrow = zrow * alpha + zs;
    mrow = m_new;
#pragma unroll
    for (int dt = 0; dt < 4; dt++) O[dt] *= alpha;

    // --- stage C: P^T -> LDS as f16 at [m][j-local] (reuses pos rows)
#pragma unroll
    for (int t = 0; t < 17; t++) {
      *(unsigned*)(row + t * 16 + 4 * q) = pk_f16(S[t][0], S[t][1]);
      *(unsigned*)(row + t * 16 + 4 * q + 2) = pk_f16(S[t][2], S[t][3]);
    }
    // zero tail cols [272, 288) so PV k-tile 8 reads zeros there
    *(unsigned*)(row + 272 + 4 * q) = 0u;
    *(unsigned*)(row + 272 + 4 * q + 2) = 0u;

    // --- stage D: O^T += V^T . P^T
#pragma unroll
    for (int kt = 0; kt < 9; kt++) {
      const f16x8 Bf = *(const f16x8*)(row + kt * 32 + q * 8);
      int j = j00 + kt * 32 + q * 8;
      j = j > (MKq - 8) ? (MKq - 8) : j;
#pragma unroll
      for (int dt = 0; dt < 4; dt++) {
        const f16x8 Vf = *(const f16x8*)(vbn + (size_t)(dt * 16 + l16) * MKq + j);
        O[dt] = mfma_f16(Vf, Bf, O[dt]);
      }
    }
  }

  // epilogue: ctx[b*M + m][head*64 + d] = O/Z  (lane owns row m = l16)
  const float zi = 1.f / zrow;
  unsigned short* cp = ctx + ((size_t)(n >> 3) * Mq + m0w + l16) * Hq + (n & 7) * Dq;
#pragma unroll
  for (int dt = 0; dt < 4; dt++)
#pragma unroll
    for (int r = 0; r < 4; r++)
      cp[dt * 16 + q * 4 + r] = f2bf(O[dt][r] * zi);
}

extern "C" void kernel_launch(void* const* d_in, const int* in_sizes, int n_in,
                              void* d_out, int out_size, void* d_ws, size_t ws_size,
                              hipStream_t stream) {
  const float* query = (const float*)d_in[0];
  const float* key   = (const float*)d_in[1];
  const float* value = (const float*)d_in[2];
  const float* pos   = (const float*)d_in[3];
  const float* Wq    = (const float*)d_in[4];
  const float* Wk    = (const float*)d_in[5];
  const float* Wv    = (const float*)d_in[6];
  const float* Wo    = (const float*)d_in[7];
  float* out = (float*)d_out;

  char* w = (char*)d_ws;
  unsigned short* qb   = (unsigned short*)w; w += (size_t)64 * Mq * Dq * 2;    // 8 MB
  unsigned short* kbuf = (unsigned short*)w; w += (size_t)64 * MKq * Dq * 2;   // 16 MB
  _Float16*       vTb  = (_Float16*)w;       w += (size_t)64 * Dq * MKq * 2;   // 16 MB
  unsigned short* posT = (unsigned short*)w; w += (size_t)SPANq * Dq * 2;      // 128 KB
  unsigned short* WTq  = (unsigned short*)w; w += (size_t)Hq * Hq * 2;
  unsigned short* WTk  = (unsigned short*)w; w += (size_t)Hq * Hq * 2;
  unsigned short* WTv  = (unsigned short*)w; w += (size_t)Hq * Hq * 2;
  unsigned short* WTo  = (unsigned short*)w; w += (size_t)Hq * Hq * 2;
  unsigned short* ctx  = (unsigned short*)w; w += (size_t)Bq * Mq * Hq * 2;    // 8 MB

  prep_transpose<<<272, 256, 0, stream>>>(Wq, Wk, Wv, Wo, pos, WTq, WTk, WTv, WTo, posT);
  gemm128<<<dim3(64, 4), 256, 0, stream>>>(query, nullptr, WTq, qb, nullptr, nullptr, 0, 10);
  gemm128<<<dim3(128, 4), 256, 0, stream>>>(key, nullptr, WTk, kbuf, nullptr, nullptr, 1, 11);
  gemm128<<<dim3(128, 4), 256, 0, stream>>>(value, nullptr, WTv, nullptr, vTb, nullptr, 2, 11);
  attn2<<<dim3(16, 64), 256, 0, stream>>>(qb, kbuf, vTb, posT, ctx);
  gemm128<<<dim3(64, 4), 256, 0, stream>>>(nullptr, ctx, WTo, nullptr, nullptr, out, 3, 10);
}

// Round 4
// 396.810 us; speedup vs baseline: 1.1129x; 1.0019x over previous
//
#include <hip/hip_runtime.h>
#include <stdint.h>

#define Bq 8
#define Mq 1024
#define Hq 512
#define NHq 8
#define Dq 64
#define SPANq 1024
#define MKq 2048
#define PR2 168   // attn LDS row stride (ushorts); 160 used, 336 B = 16B-aligned

typedef __bf16 bf16x8 __attribute__((ext_vector_type(8)));
typedef _Float16 f16x8 __attribute__((ext_vector_type(8)));
typedef float f32x4 __attribute__((ext_vector_type(4)));
typedef unsigned short ushort8 __attribute__((ext_vector_type(8)));
typedef unsigned int uint2v __attribute__((ext_vector_type(2)));

static __device__ __forceinline__ unsigned short f2bf(float f) {
  union { float f; unsigned u; } x; x.f = f;
  unsigned r = x.u + 0x7FFFu + ((x.u >> 16) & 1u);
  return (unsigned short)(r >> 16);
}

static __device__ __forceinline__ unsigned pk_f16(float a, float b) {
  return __builtin_bit_cast(unsigned, __builtin_amdgcn_cvt_pkrtz(a, b));
}

static __device__ __forceinline__ f32x4 mfma_bf16(bf16x8 a, bf16x8 b, f32x4 c) {
  return __builtin_amdgcn_mfma_f32_16x16x32_bf16(a, b, c, 0, 0, 0);
}
static __device__ __forceinline__ f32x4 mfma_f16(f16x8 a, f16x8 b, f32x4 c) {
  return __builtin_amdgcn_mfma_f32_16x16x32_f16(a, b, c, 0, 0, 0);
}

// ---------------- elementwise fp32 -> bf16 for q/k/v
__global__ __launch_bounds__(256) void conv_bf16(
    const float* __restrict__ q, const float* __restrict__ k,
    const float* __restrict__ v, unsigned short* __restrict__ qo,
    unsigned short* __restrict__ ko, unsigned short* __restrict__ vo) {
  const int z = blockIdx.y;
  const float* src = (z == 0) ? q : (z == 1) ? k : v;
  unsigned short* dst = (z == 0) ? qo : (z == 1) ? ko : vo;
  const int n = (z == 0) ? (Bq * Mq * Hq) : (Bq * MKq * Hq);
  const int idx = (blockIdx.x * 256 + threadIdx.x) * 8;
  if (idx >= n) return;
  const f32x4 f0 = *(const f32x4*)(src + idx);
  const f32x4 f1 = *(const f32x4*)(src + idx + 4);
  ushort8 h;
  h[0] = f2bf(f0[0]); h[1] = f2bf(f0[1]); h[2] = f2bf(f0[2]); h[3] = f2bf(f0[3]);
  h[4] = f2bf(f1[0]); h[5] = f2bf(f1[1]); h[6] = f2bf(f1[2]); h[7] = f2bf(f1[3]);
  *(ushort8*)(dst + idx) = h;
}

// ---------------- prep: transpose+convert weights (WT[o][i]=W[i][o]) and pos (posT[s][d]=pos[d][s])
__global__ __launch_bounds__(256) void prep_transpose(
    const float* __restrict__ Wq, const float* __restrict__ Wk,
    const float* __restrict__ Wv, const float* __restrict__ Wo,
    const float* __restrict__ pos,
    unsigned short* __restrict__ WTq, unsigned short* __restrict__ WTk,
    unsigned short* __restrict__ WTv, unsigned short* __restrict__ WTo,
    unsigned short* __restrict__ posT) {
  __shared__ float tile[64][65];
  const int bid = blockIdx.x;
  const float* src; unsigned short* dst;
  int src_stride, dst_stride, i0, o0;
  if (bid < 256) {
    const int w = bid >> 6, t = bid & 63;
    src = (w == 0) ? Wq : (w == 1) ? Wk : (w == 2) ? Wv : Wo;
    dst = (w == 0) ? WTq : (w == 1) ? WTk : (w == 2) ? WTv : WTo;
    src_stride = Hq; dst_stride = Hq;
    i0 = (t >> 3) * 64; o0 = (t & 7) * 64;
  } else {
    const int t = bid - 256;
    src = pos; dst = posT;
    src_stride = SPANq; dst_stride = Dq;
    i0 = 0; o0 = t * 64;
  }
  const int tid = threadIdx.x;
  for (int e = tid; e < 4096; e += 256) {
    const int r = e >> 6, c = e & 63;
    tile[r][c] = src[(size_t)(i0 + r) * src_stride + o0 + c];
  }
  __syncthreads();
  for (int e = tid; e < 4096; e += 256) {
    const int r = e >> 6, c = e & 63;
    dst[(size_t)(o0 + r) * dst_stride + i0 + c] = f2bf(tile[c][r]);
  }
}

// ---------------- 128x128 GEMM, C[r][c] = sum_k Xb[r][k] * WT[c][k]  (all-bf16 A)
// mode 0: -> outb[(b*8+head)*T + t][d]  bf16
// mode 2: -> vT[(b*8+head)*64 + d][t]   f16 (LDS-transposed epilogue)
// mode 3: -> outf fp32 row-major
__global__ __launch_bounds__(256) void gemm128(
    const unsigned short* __restrict__ Xb, const unsigned short* __restrict__ WT,
    unsigned short* __restrict__ outb, _Float16* __restrict__ outv,
    float* __restrict__ outf, int mode, int tshift) {
  __shared__ unsigned short sh[18432];
  unsigned short* As = sh;            // [128][40]
  unsigned short* Bs = sh + 5120;     // [128][40]
  const int tid = threadIdx.x;
  const int wave = tid >> 6, lane = tid & 63;
  const int q = lane >> 4, l16 = lane & 15;
  const int wy = wave >> 1, wx = wave & 1;
  const size_t m0 = (size_t)blockIdx.x * 128;
  const int n0 = blockIdx.y * 128;
  const int row = tid >> 1, kc0 = (tid & 1) * 16;

  f32x4 acc[4][4] = {};

  for (int k0 = 0; k0 < Hq; k0 += 32) {
    {
      const unsigned short* xp = Xb + (m0 + row) * Hq + k0 + kc0;
      *(ushort8*)(As + row * 40 + kc0) = *(const ushort8*)xp;
      *(ushort8*)(As + row * 40 + kc0 + 8) = *(const ushort8*)(xp + 8);
      const unsigned short* wp = WT + (size_t)(n0 + row) * Hq + k0 + kc0;
      *(ushort8*)(Bs + row * 40 + kc0) = *(const ushort8*)wp;
      *(ushort8*)(Bs + row * 40 + kc0 + 8) = *(const ushort8*)(wp + 8);
    }
    __syncthreads();
    bf16x8 af[4], bf[4];
#pragma unroll
    for (int mt = 0; mt < 4; mt++)
      af[mt] = *(const bf16x8*)(As + (wy * 64 + mt * 16 + l16) * 40 + q * 8);
#pragma unroll
    for (int nt = 0; nt < 4; nt++)
      bf[nt] = *(const bf16x8*)(Bs + (wx * 64 + nt * 16 + l16) * 40 + q * 8);
#pragma unroll
    for (int mt = 0; mt < 4; mt++)
#pragma unroll
      for (int nt = 0; nt < 4; nt++)
        acc[mt][nt] = mfma_bf16(af[mt], bf[nt], acc[mt][nt]);
    __syncthreads();
  }

  if (mode == 2) {
    // transpose epilogue: per-wave 64x64 tile -> vT[(b*8+head)*64 + d][t] f16
    _Float16* tr = (_Float16*)sh + wave * 4608;  // [64][72]
#pragma unroll
    for (int nt = 0; nt < 4; nt++)
#pragma unroll
      for (int mt = 0; mt < 4; mt++)
#pragma unroll
        for (int r = 0; r < 4; r++)
          tr[(nt * 16 + l16) * 72 + mt * 16 + q * 4 + r] = (_Float16)acc[mt][nt][r];
    const int head = blockIdx.y * 2 + wx;
    const int mrow0 = (int)m0 + wy * 64;
    const int Tlen = 1 << tshift;
    const int b = mrow0 >> tshift, t0 = mrow0 & (Tlen - 1);
#pragma unroll
    for (int it = 0; it < 8; it++) {
      const int dl = it * 8 + (lane >> 3), tl = (lane & 7) * 8;
      const f16x8 v = *(const f16x8*)(tr + dl * 72 + tl);
      *(f16x8*)(outv + ((size_t)((b * 8 + head) * 64 + dl)) * Tlen + t0 + tl) = v;
    }
    return;
  }

  const int Tlen = 1 << tshift;
#pragma unroll
  for (int mt = 0; mt < 4; mt++) {
#pragma unroll
    for (int nt = 0; nt < 4; nt++) {
      const int c = n0 + wx * 64 + nt * 16 + l16;
#pragma unroll
      for (int r = 0; r < 4; r++) {
        const int m = (int)m0 + wy * 64 + mt * 16 + q * 4 + r;
        const float val = acc[mt][nt][r];
        if (mode == 3) {
          outf[(size_t)m * Hq + c] = val;
        } else {
          const int b = m >> tshift, t = m & (Tlen - 1);
          const int head = c >> 6, d = c & 63;
          outb[(((size_t)(b * 8 + head) << tshift) + t) * 64 + d] = f2bf(val);
        }
      }
    }
  }
}

// ---------------- banded attention, register-resident softmax, no barriers
// block = 64 queries x one head; wave owns 16 queries; lane owns row m=lane&15.
// 8 chunks of 128 span; merged pos+K software-pipelined loop; S[9] in regs.
__global__ __launch_bounds__(256, 4) void attn2(
    const unsigned short* __restrict__ qb, const unsigned short* __restrict__ kglob,
    const _Float16* __restrict__ vT, const unsigned short* __restrict__ posT,
    unsigned short* __restrict__ ctx) {
  __shared__ unsigned short Psh[4 * 16 * PR2];  // 21504 B, wave-private rows

  const int tid = threadIdx.x;
  const int wave = tid >> 6, lane = tid & 63;
  const int q = lane >> 4, l16 = lane & 15;
  const int n = blockIdx.y;
  const int m0w = blockIdx.x * 64 + wave * 16;

  unsigned short* row = Psh + (wave * 16 + l16) * PR2;

  // Q fragments (B-operand): col m = l16, k = q*8+j over d
  const unsigned short* qbase = qb + ((size_t)n * Mq + m0w + l16) * Dq;
  const bf16x8 qf0 = *(const bf16x8*)(qbase + q * 8);
  const bf16x8 qf1 = *(const bf16x8*)(qbase + 32 + q * 8);

  const unsigned short* kbn = kglob + (size_t)n * MKq * Dq;
  const _Float16* vbn = vT + (size_t)n * Dq * MKq;

  f32x4 O[4] = {};
  float zrow = 0.f, mrow = -1e30f;

  for (int c = 0; c < 8; c++) {
    const int sbase = c * 128;
    const int j00 = m0w + sbase;

    // --- merged pos+K logits, 1-deep register pipeline, no intra-loop LDS reads
    const unsigned short* kp = kbn + (size_t)(j00 + l16) * Dq + q * 8;
    const unsigned short* pp = posT + (size_t)(sbase + l16) * Dq + q * 8;
    bf16x8 ka = *(const bf16x8*)kp, kb2 = *(const bf16x8*)(kp + 32);
    bf16x8 pa = *(const bf16x8*)pp, pb2 = *(const bf16x8*)(pp + 32);
    f32x4 S[9];
#pragma unroll
    for (int t = 0; t < 9; t++) {
      bf16x8 nka, nkb, npa, npb;
      if (t < 8) { kp += 1024; nka = *(const bf16x8*)kp; nkb = *(const bf16x8*)(kp + 32); }
      if (t < 7) { pp += 1024; npa = *(const bf16x8*)pp; npb = *(const bf16x8*)(pp + 32); }
      f32x4 a = {};
      a = mfma_bf16(ka, qf0, a);
      a = mfma_bf16(kb2, qf1, a);
      S[t] = a;
      if (t < 8) {
        f32x4 b = {};
        b = mfma_bf16(pa, qf0, b);
        b = mfma_bf16(pb2, qf1, b);
        const int cw = 16 + t * 16 + 4 * q + l16;  // skew: col = 16 + s + m
        row[cw + 0] = f2bf(b[0]);
        row[cw + 1] = f2bf(b[1]);
        row[cw + 2] = f2bf(b[2]);
        row[cw + 3] = f2bf(b[3]);
      }
      ka = nka; kb2 = nkb; pa = npa; pb2 = npb;
    }

    // --- skewed pos readback + band masks
#pragma unroll
    for (int t = 0; t < 9; t++) {
      const uint2v pv = *(const uint2v*)(row + 16 + t * 16 + 4 * q);
      S[t][0] += __uint_as_float(pv.x << 16);
      S[t][1] += __uint_as_float(pv.x & 0xffff0000u);
      S[t][2] += __uint_as_float(pv.y << 16);
      S[t][3] += __uint_as_float(pv.y & 0xffff0000u);
    }
#pragma unroll
    for (int r = 0; r < 4; r++) {
      if (4 * q + r < l16) S[0][r] = -1e30f;
      if (4 * q + r >= l16) S[8][r] = -1e30f;
    }

    // --- online softmax in registers
    float mx = -1e30f;
#pragma unroll
    for (int t = 0; t < 9; t++)
      mx = fmaxf(mx, fmaxf(fmaxf(S[t][0], S[t][1]), fmaxf(S[t][2], S[t][3])));
    mx = fmaxf(mx, __shfl_xor(mx, 16, 64));
    mx = fmaxf(mx, __shfl_xor(mx, 32, 64));
    const float m_new = fmaxf(mrow, mx);
    const float alpha = __expf((mrow - m_new) * 0.125f);
    float zs = 0.f;
#pragma unroll
    for (int t = 0; t < 9; t++) {
#pragma unroll
      for (int r = 0; r < 4; r++) {
        const float e = __expf((S[t][r] - m_new) * 0.125f);
        S[t][r] = e; zs += e;
      }
    }
    zs += __shfl_xor(zs, 16, 64);
    zs += __shfl_xor(zs, 32, 64);
    zrow = zrow * alpha + zs;
    mrow = m_new;
#pragma unroll
    for (int dt = 0; dt < 4; dt++) O[dt] *= alpha;

    // --- P -> LDS f16 at [m][j_local]; zero tail [144,160)
#pragma unroll
    for (int t = 0; t < 9; t++) {
      *(unsigned*)(row + t * 16 + 4 * q) = pk_f16(S[t][0], S[t][1]);
      *(unsigned*)(row + t * 16 + 4 * q + 2) = pk_f16(S[t][2], S[t][3]);
    }
    *(unsigned*)(row + 144 + 4 * q) = 0u;
    *(unsigned*)(row + 144 + 4 * q + 2) = 0u;

    // --- PV: O^T += V^T . P^T ; hoisted P frags + 1-deep V prefetch
    f16x8 Bf[5];
#pragma unroll
    for (int kt = 0; kt < 5; kt++)
      Bf[kt] = *(const f16x8*)(row + kt * 32 + q * 8);

    f16x8 Vc[4];
    {
      int j = j00 + q * 8;
      if (j > MKq - 8) j = MKq - 8;  // bases are multiples of 8; clamped bases have P==0
#pragma unroll
      for (int dt = 0; dt < 4; dt++)
        Vc[dt] = *(const f16x8*)(vbn + (size_t)(dt * 16 + l16) * MKq + j);
    }
#pragma unroll
    for (int kt = 0; kt < 5; kt++) {
      f16x8 Vn[4];
      if (kt < 4) {
        int jn = j00 + (kt + 1) * 32 + q * 8;
        if (jn > MKq - 8) jn = MKq - 8;
#pragma unroll
        for (int dt = 0; dt < 4; dt++)
          Vn[dt] = *(const f16x8*)(vbn + (size_t)(dt * 16 + l16) * MKq + jn);
      }
#pragma unroll
      for (int dt = 0; dt < 4; dt++)
        O[dt] = mfma_f16(Vc[dt], Bf[kt], O[dt]);
#pragma unroll
      for (int dt = 0; dt < 4; dt++) Vc[dt] = Vn[dt];
    }
  }

  // epilogue: ctx[b*M + m][head*64 + d] = O/Z  (lane owns row m = l16)
  const float zi = 1.f / zrow;
  unsigned short* cp = ctx + ((size_t)(n >> 3) * Mq + m0w + l16) * Hq + (n & 7) * Dq;
#pragma unroll
  for (int dt = 0; dt < 4; dt++)
#pragma unroll
    for (int r = 0; r < 4; r++)
      cp[dt * 16 + q * 4 + r] = f2bf(O[dt][r] * zi);
}

extern "C" void kernel_launch(void* const* d_in, const int* in_sizes, int n_in,
                              void* d_out, int out_size, void* d_ws, size_t ws_size,
                              hipStream_t stream) {
  const float* query = (const float*)d_in[0];
  const float* key   = (const float*)d_in[1];
  const float* value = (const float*)d_in[2];
  const float* pos   = (const float*)d_in[3];
  const float* Wq    = (const float*)d_in[4];
  const float* Wk    = (const float*)d_in[5];
  const float* Wv    = (const float*)d_in[6];
  const float* Wo    = (const float*)d_in[7];
  float* out = (float*)d_out;

  char* w = (char*)d_ws;
  unsigned short* qX   = (unsigned short*)w; w += (size_t)Bq * Mq * Hq * 2;    // 8 MB
  unsigned short* kX   = (unsigned short*)w; w += (size_t)Bq * MKq * Hq * 2;   // 16 MB
  unsigned short* vX   = (unsigned short*)w; w += (size_t)Bq * MKq * Hq * 2;   // 16 MB
  unsigned short* qb   = (unsigned short*)w; w += (size_t)64 * Mq * Dq * 2;    // 8 MB
  unsigned short* kbuf = (unsigned short*)w; w += (size_t)64 * MKq * Dq * 2;   // 16 MB
  _Float16*       vTb  = (_Float16*)w;       w += (size_t)64 * Dq * MKq * 2;   // 16 MB
  unsigned short* posT = (unsigned short*)w; w += (size_t)SPANq * Dq * 2;      // 128 KB
  unsigned short* WTq  = (unsigned short*)w; w += (size_t)Hq * Hq * 2;
  unsigned short* WTk  = (unsigned short*)w; w += (size_t)Hq * Hq * 2;
  unsigned short* WTv  = (unsigned short*)w; w += (size_t)Hq * Hq * 2;
  unsigned short* WTo  = (unsigned short*)w; w += (size_t)Hq * Hq * 2;
  unsigned short* ctx  = (unsigned short*)w; w += (size_t)Bq * Mq * Hq * 2;    // 8 MB

  prep_transpose<<<272, 256, 0, stream>>>(Wq, Wk, Wv, Wo, pos, WTq, WTk, WTv, WTo, posT);
  conv_bf16<<<dim3(4096, 3), 256, 0, stream>>>(query, key, value, qX, kX, vX);
  gemm128<<<dim3(64, 4), 256, 0, stream>>>(qX, WTq, qb, nullptr, nullptr, 0, 10);
  gemm128<<<dim3(128, 4), 256, 0, stream>>>(kX, WTk, kbuf, nullptr, nullptr, 0, 11);
  gemm128<<<dim3(128, 4), 256, 0, stream>>>(vX, WTv, nullptr, vTb, nullptr, 2, 11);
  attn2<<<dim3(16, 64), 256, 0, stream>>>(qb, kbuf, vTb, posT, ctx);
  gemm128<<<dim3(64, 4), 256, 0, stream>>>(ctx, WTo, nullptr, nullptr, out, 3, 10);
}

// Round 5
// 286.924 us; speedup vs baseline: 1.5391x; 1.3830x over previous
//
#include <hip/hip_runtime.h>
#include <stdint.h>

#define Bq 8
#define Mq 1024
#define Hq 512
#define NHq 8
#define Dq 64
#define SPANq 1024
#define MKq 2048
#define PR2 168   // attn P-row stride (ushorts); 160 used

typedef __bf16 bf16x8 __attribute__((ext_vector_type(8)));
typedef _Float16 f16x8 __attribute__((ext_vector_type(8)));
typedef float f32x4 __attribute__((ext_vector_type(4)));
typedef unsigned short ushort8 __attribute__((ext_vector_type(8)));
typedef unsigned int uint2v __attribute__((ext_vector_type(2)));

static __device__ __forceinline__ unsigned short f2bf(float f) {
  union { float f; unsigned u; } x; x.f = f;
  unsigned r = x.u + 0x7FFFu + ((x.u >> 16) & 1u);
  return (unsigned short)(r >> 16);
}

static __device__ __forceinline__ unsigned pk_f16(float a, float b) {
  return __builtin_bit_cast(unsigned, __builtin_amdgcn_cvt_pkrtz(a, b));
}

static __device__ __forceinline__ f32x4 mfma_bf16(bf16x8 a, bf16x8 b, f32x4 c) {
  return __builtin_amdgcn_mfma_f32_16x16x32_bf16(a, b, c, 0, 0, 0);
}
static __device__ __forceinline__ f32x4 mfma_f16(f16x8 a, f16x8 b, f32x4 c) {
  return __builtin_amdgcn_mfma_f32_16x16x32_f16(a, b, c, 0, 0, 0);
}

// async 16B/lane global->LDS DMA; lds dest = uniform base + lane*16
static __device__ __forceinline__ void async_ld16(const void* g, void* l) {
  __builtin_amdgcn_global_load_lds(
      (const __attribute__((address_space(1))) void*)g,
      (__attribute__((address_space(3))) void*)l, 16, 0, 0);
}

// ---------------- elementwise fp32 -> bf16 for q/k/v
__global__ __launch_bounds__(256) void conv_bf16(
    const float* __restrict__ q, const float* __restrict__ k,
    const float* __restrict__ v, unsigned short* __restrict__ qo,
    unsigned short* __restrict__ ko, unsigned short* __restrict__ vo) {
  const int z = blockIdx.y;
  const float* src = (z == 0) ? q : (z == 1) ? k : v;
  unsigned short* dst = (z == 0) ? qo : (z == 1) ? ko : vo;
  const int n = (z == 0) ? (Bq * Mq * Hq) : (Bq * MKq * Hq);
  const int idx = (blockIdx.x * 256 + threadIdx.x) * 8;
  if (idx >= n) return;
  const f32x4 f0 = *(const f32x4*)(src + idx);
  const f32x4 f1 = *(const f32x4*)(src + idx + 4);
  ushort8 h;
  h[0] = f2bf(f0[0]); h[1] = f2bf(f0[1]); h[2] = f2bf(f0[2]); h[3] = f2bf(f0[3]);
  h[4] = f2bf(f1[0]); h[5] = f2bf(f1[1]); h[6] = f2bf(f1[2]); h[7] = f2bf(f1[3]);
  *(ushort8*)(dst + idx) = h;
}

// ---------------- prep: transpose+convert weights (WT[o][i]=W[i][o]) and pos (posT[s][d]=pos[d][s])
__global__ __launch_bounds__(256) void prep_transpose(
    const float* __restrict__ Wq, const float* __restrict__ Wk,
    const float* __restrict__ Wv, const float* __restrict__ Wo,
    const float* __restrict__ pos,
    unsigned short* __restrict__ WTq, unsigned short* __restrict__ WTk,
    unsigned short* __restrict__ WTv, unsigned short* __restrict__ WTo,
    unsigned short* __restrict__ posT) {
  __shared__ float tile[64][65];
  const int bid = blockIdx.x;
  const float* src; unsigned short* dst;
  int src_stride, dst_stride, i0, o0;
  if (bid < 256) {
    const int w = bid >> 6, t = bid & 63;
    src = (w == 0) ? Wq : (w == 1) ? Wk : (w == 2) ? Wv : Wo;
    dst = (w == 0) ? WTq : (w == 1) ? WTk : (w == 2) ? WTv : WTo;
    src_stride = Hq; dst_stride = Hq;
    i0 = (t >> 3) * 64; o0 = (t & 7) * 64;
  } else {
    const int t = bid - 256;
    src = pos; dst = posT;
    src_stride = SPANq; dst_stride = Dq;
    i0 = 0; o0 = t * 64;
  }
  const int tid = threadIdx.x;
  for (int e = tid; e < 4096; e += 256) {
    const int r = e >> 6, c = e & 63;
    tile[r][c] = src[(size_t)(i0 + r) * src_stride + o0 + c];
  }
  __syncthreads();
  for (int e = tid; e < 4096; e += 256) {
    const int r = e >> 6, c = e & 63;
    dst[(size_t)(o0 + r) * dst_stride + i0 + c] = f2bf(tile[c][r]);
  }
}

// ---------------- 128x128 GEMM via global_load_lds staging (BK=64, XOR-swizzled)
// C[r][c] = sum_k Xb[r][k] * WT[c][k]
// mode 0: -> outb[(b*8+head)*T + t][d]  bf16
// mode 2: -> vT[(b*8+head)*64 + d][t]   f16 (LDS-transposed epilogue)
// mode 3: -> outf fp32 row-major
__global__ __launch_bounds__(256, 2) void gemm128(
    const unsigned short* __restrict__ Xb, const unsigned short* __restrict__ WT,
    unsigned short* __restrict__ outb, _Float16* __restrict__ outv,
    float* __restrict__ outf, int mode, int tshift) {
  __shared__ unsigned short sh[18432];   // 36 KB (tiles use 32 KB; mode-2 epilogue reuses)
  unsigned short* As = sh;               // [128][64] unpadded, swizzled
  unsigned short* Bs = sh + 8192;
  const int tid = threadIdx.x;
  const int wave = tid >> 6, lane = tid & 63;
  const int q = lane >> 4, l16 = lane & 15;
  const int wy = wave >> 1, wx = wave & 1;
  const size_t m0 = (size_t)blockIdx.x * 128;
  const int n0 = blockIdx.y * 128;
  const int dsub = lane >> 3;                 // row offset within slot
  const int dswz = (lane & 7) ^ dsub;         // swizzled source chunk

  f32x4 acc[4][4] = {};

  for (int k0 = 0; k0 < Hq; k0 += 64) {
    __syncthreads();
#pragma unroll
    for (int i = 0; i < 4; i++) {
      const int s = wave * 4 + i;             // slot 0..15, 8 rows each
      const int r = s * 8 + dsub;             // row 0..127
      async_ld16(Xb + (m0 + r) * Hq + k0 + dswz * 8, As + s * 512);
      async_ld16(WT + (size_t)(n0 + r) * Hq + k0 + dswz * 8, Bs + s * 512);
    }
    __syncthreads();
    bf16x8 af[2][4], bg[2][4];
#pragma unroll
    for (int h = 0; h < 2; h++) {
#pragma unroll
      for (int mt = 0; mt < 4; mt++) {
        const int R = wy * 64 + mt * 16 + l16;
        af[h][mt] = *(const bf16x8*)(As + R * 64 + (((h * 4 + q) ^ (l16 & 7)) * 8));
      }
#pragma unroll
      for (int nt = 0; nt < 4; nt++) {
        const int R = wx * 64 + nt * 16 + l16;
        bg[h][nt] = *(const bf16x8*)(Bs + R * 64 + (((h * 4 + q) ^ (l16 & 7)) * 8));
      }
    }
#pragma unroll
    for (int h = 0; h < 2; h++)
#pragma unroll
      for (int mt = 0; mt < 4; mt++)
#pragma unroll
        for (int nt = 0; nt < 4; nt++)
          acc[mt][nt] = mfma_bf16(af[h][mt], bg[h][nt], acc[mt][nt]);
  }

  if (mode == 2) {
    __syncthreads();  // protect tile LDS before reuse
    // transpose epilogue: per-wave 64x64 tile -> vT[(b*8+head)*64 + d][t] f16
    _Float16* tr = (_Float16*)sh + wave * 4608;  // [64][72]
#pragma unroll
    for (int nt = 0; nt < 4; nt++)
#pragma unroll
      for (int mt = 0; mt < 4; mt++)
#pragma unroll
        for (int r = 0; r < 4; r++)
          tr[(nt * 16 + l16) * 72 + mt * 16 + q * 4 + r] = (_Float16)acc[mt][nt][r];
    const int head = blockIdx.y * 2 + wx;
    const int mrow0 = (int)m0 + wy * 64;
    const int Tlen = 1 << tshift;
    const int b = mrow0 >> tshift, t0 = mrow0 & (Tlen - 1);
#pragma unroll
    for (int it = 0; it < 8; it++) {
      const int dl = it * 8 + (lane >> 3), tl = (lane & 7) * 8;
      const f16x8 v = *(const f16x8*)(tr + dl * 72 + tl);
      *(f16x8*)(outv + ((size_t)((b * 8 + head) * 64 + dl)) * Tlen + t0 + tl) = v;
    }
    return;
  }

  const int Tlen = 1 << tshift;
#pragma unroll
  for (int mt = 0; mt < 4; mt++) {
#pragma unroll
    for (int nt = 0; nt < 4; nt++) {
      const int c = n0 + wx * 64 + nt * 16 + l16;
#pragma unroll
      for (int r = 0; r < 4; r++) {
        const int m = (int)m0 + wy * 64 + mt * 16 + q * 4 + r;
        const float val = acc[mt][nt][r];
        if (mode == 3) {
          outf[(size_t)m * Hq + c] = val;
        } else {
          const int b = m >> tshift, t = m & (Tlen - 1);
          const int head = c >> 6, d = c & 63;
          outb[(((size_t)(b * 8 + head) << tshift) + t) * 64 + d] = f2bf(val);
        }
      }
    }
  }
}

// ---------------- banded attention: LDS-staged K+pos via swizzled DMA
// block = 64 queries x one head; wave owns 16 queries; lane owns row m=lane&15.
__global__ __launch_bounds__(256, 2) void attn3(
    const unsigned short* __restrict__ qb, const unsigned short* __restrict__ kglob,
    const _Float16* __restrict__ vT, const unsigned short* __restrict__ posT,
    unsigned short* __restrict__ ctx) {
  __shared__ unsigned short Kt[12288];          // K tile: 192 rows x 64 d (swizzled)
  __shared__ unsigned short Pt[8192];           // pos tile: 128 rows x 64 d (swizzled)
  __shared__ unsigned short Psh[4 * 16 * PR2];  // P / pos-skew rows (wave-private)

  const int tid = threadIdx.x;
  const int wave = tid >> 6, lane = tid & 63;
  const int q = lane >> 4, l16 = lane & 15;
  const int n = blockIdx.y;
  const int m0 = blockIdx.x * 64;
  const int m0w = m0 + wave * 16;
  const int dsub = lane >> 3;
  const int dswz = (lane & 7) ^ dsub;

  unsigned short* row = Psh + (wave * 16 + l16) * PR2;

  // Q fragments (B-operand): col m = l16, k = q*8+j over d
  const unsigned short* qbase = qb + ((size_t)n * Mq + m0w + l16) * Dq;
  const bf16x8 qf0 = *(const bf16x8*)(qbase + q * 8);
  const bf16x8 qf1 = *(const bf16x8*)(qbase + 32 + q * 8);

  const unsigned short* kbn = kglob + (size_t)n * MKq * Dq;
  const _Float16* vbn = vT + (size_t)n * Dq * MKq;

  f32x4 O[4] = {};
  float zrow = 0.f, mrow = -1e30f;

  for (int c = 0; c < 8; c++) {
    const int sbase = c * 128;
    const int jb = m0 + sbase;       // K tile base row (block-level)
    const int j00 = m0w + sbase;     // wave's base

    __syncthreads();  // previous chunk's tile reads complete
    // --- DMA K tile: 24 slots x 1 KB; pos tile: 16 slots
#pragma unroll
    for (int i = 0; i < 6; i++) {
      const int s = wave + 4 * i;
      const int r = s * 8 + dsub;    // 0..191
      async_ld16(kbn + (size_t)(jb + r) * Dq + dswz * 8, Kt + s * 512);
    }
#pragma unroll
    for (int i = 0; i < 4; i++) {
      const int s = wave + 4 * i;
      const int r = s * 8 + dsub;    // 0..127
      async_ld16(posT + (size_t)(sbase + r) * Dq + dswz * 8, Pt + s * 512);
    }
    __syncthreads();  // DMA drained (compiler emits vmcnt(0) before barrier)

    // --- pos logits -> skewed rows: col = 16 + s_local + m
#pragma unroll
    for (int t = 0; t < 8; t++) {
      const int rl = t * 16 + l16;
      const int ch = (q ^ (l16 & 7)) * 8;
      const bf16x8 p0 = *(const bf16x8*)(Pt + rl * 64 + ch);
      const bf16x8 p1 = *(const bf16x8*)(Pt + rl * 64 + (ch ^ 32));
      f32x4 b = {};
      b = mfma_bf16(p0, qf0, b);
      b = mfma_bf16(p1, qf1, b);
      const int cw = 16 + t * 16 + 4 * q + l16;
      row[cw + 0] = f2bf(b[0]);
      row[cw + 1] = f2bf(b[1]);
      row[cw + 2] = f2bf(b[2]);
      row[cw + 3] = f2bf(b[3]);
    }

    // --- ctx logits S^T[j][m] from K tile + skewed pos readback + band masks
    f32x4 S[9];
#pragma unroll
    for (int t = 0; t < 9; t++) {
      const int rl = wave * 16 + t * 16 + l16;  // 0..191
      const int ch = (q ^ (l16 & 7)) * 8;
      const bf16x8 k0 = *(const bf16x8*)(Kt + rl * 64 + ch);
      const bf16x8 k1 = *(const bf16x8*)(Kt + rl * 64 + (ch ^ 32));
      f32x4 a = {};
      a = mfma_bf16(k0, qf0, a);
      a = mfma_bf16(k1, qf1, a);
      const uint2v pv = *(const uint2v*)(row + 16 + t * 16 + 4 * q);
      a[0] += __uint_as_float(pv.x << 16);
      a[1] += __uint_as_float(pv.x & 0xffff0000u);
      a[2] += __uint_as_float(pv.y << 16);
      a[3] += __uint_as_float(pv.y & 0xffff0000u);
      S[t] = a;
    }
#pragma unroll
    for (int r = 0; r < 4; r++) {
      if (4 * q + r < l16) S[0][r] = -1e30f;
      if (4 * q + r >= l16) S[8][r] = -1e30f;
    }

    // --- online softmax in registers
    float mx = -1e30f;
#pragma unroll
    for (int t = 0; t < 9; t++)
      mx = fmaxf(mx, fmaxf(fmaxf(S[t][0], S[t][1]), fmaxf(S[t][2], S[t][3])));
    mx = fmaxf(mx, __shfl_xor(mx, 16, 64));
    mx = fmaxf(mx, __shfl_xor(mx, 32, 64));
    const float m_new = fmaxf(mrow, mx);
    const float alpha = __expf((mrow - m_new) * 0.125f);
    float zs = 0.f;
#pragma unroll
    for (int t = 0; t < 9; t++) {
#pragma unroll
      for (int r = 0; r < 4; r++) {
        const float e = __expf((S[t][r] - m_new) * 0.125f);
        S[t][r] = e; zs += e;
      }
    }
    zs += __shfl_xor(zs, 16, 64);
    zs += __shfl_xor(zs, 32, 64);
    zrow = zrow * alpha + zs;
    mrow = m_new;
#pragma unroll
    for (int dt = 0; dt < 4; dt++) O[dt] *= alpha;

    // --- P -> LDS f16 at [m][j_local]; zero tail [144,160)
#pragma unroll
    for (int t = 0; t < 9; t++) {
      *(unsigned*)(row + t * 16 + 4 * q) = pk_f16(S[t][0], S[t][1]);
      *(unsigned*)(row + t * 16 + 4 * q + 2) = pk_f16(S[t][2], S[t][3]);
    }
    *(unsigned*)(row + 144 + 4 * q) = 0u;
    *(unsigned*)(row + 144 + 4 * q + 2) = 0u;

    // --- PV: O^T += V^T . P^T  (V direct from global; batch all 20 loads)
    f16x8 Bf[5];
#pragma unroll
    for (int kt = 0; kt < 5; kt++)
      Bf[kt] = *(const f16x8*)(row + kt * 32 + q * 8);
    f16x8 Vv[5][4];
#pragma unroll
    for (int kt = 0; kt < 5; kt++) {
      int j = j00 + kt * 32 + q * 8;
      if (j > MKq - 8) j = MKq - 8;  // clamped cols have P==0
#pragma unroll
      for (int dt = 0; dt < 4; dt++)
        Vv[kt][dt] = *(const f16x8*)(vbn + (size_t)(dt * 16 + l16) * MKq + j);
    }
#pragma unroll
    for (int kt = 0; kt < 5; kt++)
#pragma unroll
      for (int dt = 0; dt < 4; dt++)
        O[dt] = mfma_f16(Vv[kt][dt], Bf[kt], O[dt]);
  }

  // epilogue: ctx[b*M + m][head*64 + d] = O/Z  (lane owns row m = l16)
  const float zi = 1.f / zrow;
  unsigned short* cp = ctx + ((size_t)(n >> 3) * Mq + m0w + l16) * Hq + (n & 7) * Dq;
#pragma unroll
  for (int dt = 0; dt < 4; dt++)
#pragma unroll
    for (int r = 0; r < 4; r++)
      cp[dt * 16 + q * 4 + r] = f2bf(O[dt][r] * zi);
}

extern "C" void kernel_launch(void* const* d_in, const int* in_sizes, int n_in,
                              void* d_out, int out_size, void* d_ws, size_t ws_size,
                              hipStream_t stream) {
  const float* query = (const float*)d_in[0];
  const float* key   = (const float*)d_in[1];
  const float* value = (const float*)d_in[2];
  const float* pos   = (const float*)d_in[3];
  const float* Wq    = (const float*)d_in[4];
  const float* Wk    = (const float*)d_in[5];
  const float* Wv    = (const float*)d_in[6];
  const float* Wo    = (const float*)d_in[7];
  float* out = (float*)d_out;

  char* w = (char*)d_ws;
  unsigned short* qX   = (unsigned short*)w; w += (size_t)Bq * Mq * Hq * 2;    // 8 MB
  unsigned short* kX   = (unsigned short*)w; w += (size_t)Bq * MKq * Hq * 2;   // 16 MB
  unsigned short* vX   = (unsigned short*)w; w += (size_t)Bq * MKq * Hq * 2;   // 16 MB
  unsigned short* qb   = (unsigned short*)w; w += (size_t)64 * Mq * Dq * 2;    // 8 MB
  unsigned short* kbuf = (unsigned short*)w; w += (size_t)64 * MKq * Dq * 2;   // 16 MB
  _Float16*       vTb  = (_Float16*)w;       w += (size_t)64 * Dq * MKq * 2;   // 16 MB
  unsigned short* posT = (unsigned short*)w; w += (size_t)SPANq * Dq * 2;      // 128 KB
  unsigned short* WTq  = (unsigned short*)w; w += (size_t)Hq * Hq * 2;
  unsigned short* WTk  = (unsigned short*)w; w += (size_t)Hq * Hq * 2;
  unsigned short* WTv  = (unsigned short*)w; w += (size_t)Hq * Hq * 2;
  unsigned short* WTo  = (unsigned short*)w; w += (size_t)Hq * Hq * 2;
  unsigned short* ctx  = (unsigned short*)w; w += (size_t)Bq * Mq * Hq * 2;    // 8 MB

  prep_transpose<<<272, 256, 0, stream>>>(Wq, Wk, Wv, Wo, pos, WTq, WTk, WTv, WTo, posT);
  conv_bf16<<<dim3(4096, 3), 256, 0, stream>>>(query, key, value, qX, kX, vX);
  gemm128<<<dim3(64, 4), 256, 0, stream>>>(qX, WTq, qb, nullptr, nullptr, 0, 10);
  gemm128<<<dim3(128, 4), 256, 0, stream>>>(kX, WTk, kbuf, nullptr, nullptr, 0, 11);
  gemm128<<<dim3(128, 4), 256, 0, stream>>>(vX, WTv, nullptr, vTb, nullptr, 2, 11);
  attn3<<<dim3(16, 64), 256, 0, stream>>>(qb, kbuf, vTb, posT, ctx);
  gemm128<<<dim3(64, 4), 256, 0, stream>>>(ctx, WTo, nullptr, nullptr, out, 3, 10);
}